// Round 8
// baseline (281.649 us; speedup 1.0000x reference)
//
#include <hip/hip_runtime.h>
#include <stdint.h>

// Problem constants (B=4, S=2048 -> M = 8192 rows)
#define M_TOT 8192
#define N_TOT 4096
#define K_TOT 4096

typedef int v4i __attribute__((ext_vector_type(4)));

// GEMM tile config: 256x256 tile, K-step 64 B, 8 waves (2M x 4N), 512 thr.
// A staged in LDS (4 x 16 KB buffers = 64 KB -> 2 blocks/CU).
// B read direct global->register (L2-resident via n-contiguous XCD swizzle).
#define BM 256
#define BN 256
#define SUB 64
#define NS (K_TOT / SUB)                  // 64 K-step iterations
#define A_SUB (BM * SUB)                  // 16 KB
#define BUF_BYTES A_SUB                   // 16 KB; x4 buffers = 64 KB LDS

// ---------------------------------------------------------------------------
// Kernel 1: fused pre-pass: pack weight int32->int8 + global max(|x/smooth|).
// Grid stride (524288) is a multiple of K/4=1024 -> each thread's smooth
// slice is loop-invariant; reciprocals hoisted.
// ---------------------------------------------------------------------------
__global__ void prep_reduce(const int4* __restrict__ w32, int* __restrict__ w8,
                            int nw4, const float4* __restrict__ smooth4,
                            const float4* __restrict__ x,
                            unsigned int* __restrict__ maxbits, int nx4) {
  const int stride = gridDim.x * blockDim.x;
  const int g0 = blockIdx.x * blockDim.x + threadIdx.x;
  for (int i = g0; i < nw4; i += stride) {
    int4 v = w32[i];
    w8[i] = (v.x & 0xff) | ((v.y & 0xff) << 8) | ((v.z & 0xff) << 16) | (v.w << 24);
  }
  float4 s = smooth4[g0 & (K_TOT / 4 - 1)];
  const float rx = 1.0f / s.x, ry = 1.0f / s.y, rz = 1.0f / s.z, rw = 1.0f / s.w;
  float m = 0.0f;
  for (int i = g0; i < nx4; i += stride) {
    float4 v = x[i];
    m = fmaxf(m, fabsf(v.x * rx));
    m = fmaxf(m, fabsf(v.y * ry));
    m = fmaxf(m, fabsf(v.z * rz));
    m = fmaxf(m, fabsf(v.w * rw));
  }
#pragma unroll
  for (int off = 32; off; off >>= 1) m = fmaxf(m, __shfl_xor(m, off));
  __shared__ float sm[4];
  if ((threadIdx.x & 63) == 0) sm[threadIdx.x >> 6] = m;
  __syncthreads();
  if (threadIdx.x == 0) {
    float mm = fmaxf(fmaxf(sm[0], sm[1]), fmaxf(sm[2], sm[3]));
    atomicMax(maxbits, __float_as_uint(mm));
  }
}

// ---------------------------------------------------------------------------
// Kernel 2: quantize x -> int8 packed; rinv = (1/s) * (1/d) hoisted per thread
// ---------------------------------------------------------------------------
__global__ void quantize_x(const float4* __restrict__ x,
                           const float4* __restrict__ smooth4,
                           const unsigned int* __restrict__ maxbits,
                           int* __restrict__ xq, int n4) {
  const float d = __uint_as_float(*maxbits) / 127.0f + 1e-5f;
  const float inv = 1.0f / d;
  const int stride = gridDim.x * blockDim.x;
  const int g0 = blockIdx.x * blockDim.x + threadIdx.x;
  float4 s = smooth4[g0 & (K_TOT / 4 - 1)];
  const float rx = inv / s.x, ry = inv / s.y, rz = inv / s.z, rw = inv / s.w;
  for (int i = g0; i < n4; i += stride) {
    float4 v = x[i];
    int q0 = (int)fminf(fmaxf(rintf(v.x * rx), -128.0f), 127.0f);
    int q1 = (int)fminf(fmaxf(rintf(v.y * ry), -128.0f), 127.0f);
    int q2 = (int)fminf(fmaxf(rintf(v.z * rz), -128.0f), 127.0f);
    int q3 = (int)fminf(fmaxf(rintf(v.w * rw), -128.0f), 127.0f);
    xq[i] = (q0 & 0xff) | ((q1 & 0xff) << 8) | ((q2 & 0xff) << 16) | (q3 << 24);
  }
}

// ---------------------------------------------------------------------------
// Kernel 3: int8 GEMM. A: LDS (4-buffer, 3-deep DMA prefetch, R6's verified
// zero-conflict swizzle). B: direct global->register, prefetched 1 iter ahead
// (register ping-pong bE/bO), served from L2 (n-contiguous XCD swizzle keeps
// each XCD's B working set at 2 MB).
//
// Per-iter VMEM issue order (fenced by sched_barrier(0), nothing else emits
// VMEM in the loop): [4 b(s+1) loads][2 A-DMA(s+3)].
// Ledger at iter-s MFMA: A(s+1)2, b(s)4, A(s+2)2, b(s+1)4, A(s+3)2 = 14.
// Compiler's auto-wait for b(s) => vmcnt<=8, which also completes A(s+1).
// Trailing explicit vmcnt(8) + barrier => all waves see A(s+1) before iter
// s+1 reads buf[(s+1)&3]. Stage at iter s+1 overwrites buf[s&3], whose reads
// completed before iter s's barrier (consumed by MFMA). vmcnt never 0 (T4).
// Prologue: [bE 4][A0,A1,A2 6] -> vmcnt(4) completes bE + A0.
//
// LDS swizzle (R6, measured SQ_LDS_BANK_CONFLICT == 0):
//   read slot = (lhi ^ ((l16>>1)&3))*16; stage gcol = ((lane&3)^((lane>>3)&3))*16
// ---------------------------------------------------------------------------
__global__ __launch_bounds__(512, 2) void gemm_i8(
    const int8_t* __restrict__ Aq,   // [M][K]
    const int8_t* __restrict__ Wt,   // [N][K]
    const unsigned int* __restrict__ maxbits,
    const float* __restrict__ wscale,  // [N]
    const float* __restrict__ bias,    // [N]
    float* __restrict__ out) {         // [M][N]
  __shared__ int8_t lds[4 * BUF_BYTES];

  const int tid = threadIdx.x;
  const int lane = tid & 63;
  const int wid = tid >> 6;      // 0..7
  const int l16 = lane & 15;
  const int lhi = lane >> 4;     // 0..3

  // T1 (n-contiguous per XCD): XCD r owns n-panels {2r, 2r+1} (2 MB of B,
  // L2-resident) across all 32 m-panels. 512 blocks -> bijective.
  const int flat = blockIdx.y * gridDim.x + blockIdx.x;
  const int xcd = flat & 7;
  const int idx = flat >> 3;                 // 0..63
  const int n0 = (xcd * 2 + (idx & 1)) * BN;
  const int m0 = (idx >> 1) * BM;

  const int wave_m = wid >> 2;   // 0..1  -> 128 rows
  const int wave_n = wid & 3;    // 0..3  -> 64 cols

  // ---- A staging: per wave 2 chunks, 1 KB each (16 rows x 64 B)
  const int row_l = lane >> 2;                             // row in chunk 0..15
  const int gcol = ((lane & 3) ^ ((lane >> 3) & 3)) << 4;  // pre-swizzled slot
  const int8_t* Abase = Aq + (size_t)m0 * K_TOT;           // uniform
  int goff[2];
#pragma unroll
  for (int c = 0; c < 2; ++c) {
    int grow = (wid * 2 + c) * 16 + row_l;                 // 0..255
    goff[c] = grow * K_TOT + gcol;
  }

  auto stage = [&](int dstbuf, int koff) {
#pragma unroll
    for (int c = 0; c < 2; ++c) {
      __builtin_amdgcn_global_load_lds(
          (const __attribute__((address_space(1))) void*)(Abase + goff[c] + koff),
          (__attribute__((address_space(3))) void*)(lds + dstbuf * BUF_BYTES + (wid * 2 + c) * 1024),
          16, 0, 0);
    }
  };

  // ---- A fragment ds_read addressing (R6 verified swizzle) ----
  const int slot = (lhi ^ ((l16 >> 1) & 3)) << 4;
  const int aOff = (wave_m * 128 + l16) * SUB + slot;

  // ---- B direct-global addressing: frag j, row n0+wn*64+j*16+l16, 16B @ lhi
  const int8_t* Bg = Wt + (size_t)(n0 + wave_n * 64 + l16) * K_TOT + lhi * 16;

  v4i acc[8][4] = {};
  v4i bE[4], bO[4];

  // ---- prologue ----
#pragma unroll
  for (int j = 0; j < 4; ++j) bE[j] = *(const v4i*)(Bg + j * 16 * K_TOT);
  __builtin_amdgcn_sched_barrier(0);
  stage(0, 0);
  stage(1, SUB);
  stage(2, 2 * SUB);
  __builtin_amdgcn_sched_barrier(0);
  asm volatile("s_waitcnt vmcnt(4)" ::: "memory");
  __builtin_amdgcn_s_barrier();
  __builtin_amdgcn_sched_barrier(0);

  auto body = [&](int s, v4i (&cur)[4], v4i (&nxt)[4]) {
    const int8_t* Ab = lds + (s & 3) * BUF_BYTES;

    __builtin_amdgcn_sched_barrier(0);
    const int kn = ((s + 1 < NS) ? s + 1 : NS - 1) * SUB;
#pragma unroll
    for (int j = 0; j < 4; ++j) nxt[j] = *(const v4i*)(Bg + j * 16 * K_TOT + kn);
    __builtin_amdgcn_sched_barrier(0);
    const int ts = ((s + 3 < NS) ? s + 3 : NS - 1) * SUB;
    stage((s + 3) & 3, ts);
    __builtin_amdgcn_sched_barrier(0);

    v4i a[8];
#pragma unroll
    for (int i = 0; i < 8; ++i) a[i] = *(const v4i*)(Ab + aOff + i * 1024);

    __builtin_amdgcn_s_setprio(1);
#pragma unroll
    for (int i = 0; i < 8; ++i)
#pragma unroll
      for (int j = 0; j < 4; ++j)
        acc[i][j] = __builtin_amdgcn_mfma_i32_16x16x64_i8(a[i], cur[j], acc[i][j], 0, 0, 0);
    __builtin_amdgcn_s_setprio(0);
    __builtin_amdgcn_sched_barrier(0);

    asm volatile("s_waitcnt vmcnt(8)" ::: "memory");
    __builtin_amdgcn_sched_barrier(0);
    __builtin_amdgcn_s_barrier();
    __builtin_amdgcn_sched_barrier(0);
  };

  for (int s = 0; s < NS; s += 2) {
    body(s, bE, bO);
    body(s + 1, bO, bE);
  }

  // ---- epilogue: dequant + bias, C/D layout col=l16, row=lhi*4+reg ----
  const float ascale = __uint_as_float(*maxbits) / 127.0f;
#pragma unroll
  for (int i = 0; i < 8; ++i) {
    const int orow = m0 + wave_m * 128 + i * 16 + lhi * 4;
#pragma unroll
    for (int j = 0; j < 4; ++j) {
      const int ocol = n0 + wave_n * 64 + j * 16 + l16;
      const float wsc = wscale[ocol] * ascale;
      const float bb = bias[ocol];
#pragma unroll
      for (int r = 0; r < 4; ++r) {
        out[(size_t)(orow + r) * N_TOT + ocol] = (float)acc[i][j][r] * wsc + bb;
      }
    }
  }
}

// ---------------------------------------------------------------------------
extern "C" void kernel_launch(void* const* d_in, const int* in_sizes, int n_in,
                              void* d_out, int out_size, void* d_ws, size_t ws_size,
                              hipStream_t stream) {
  const float* x = (const float*)d_in[0];
  const int* w32 = (const int*)d_in[1];        // int8 in reference, int32 on device
  const float* wscale = (const float*)d_in[2];
  const float* smooth = (const float*)d_in[3];
  const float* bias = (const float*)d_in[4];
  float* out = (float*)d_out;

  unsigned int* maxbits = (unsigned int*)d_ws;
  int8_t* xq = (int8_t*)d_ws + (1 << 20);                    // 32 MB
  int8_t* wq8 = xq + (size_t)M_TOT * K_TOT;                  // 16 MB

  hipMemsetAsync(d_ws, 0, 4, stream);  // zero the max accumulator each call

  const int nw4 = N_TOT * K_TOT / 4;
  const int n4 = M_TOT * K_TOT / 4;
  prep_reduce<<<2048, 256, 0, stream>>>((const int4*)w32, (int*)wq8, nw4,
                                        (const float4*)smooth, (const float4*)x,
                                        maxbits, n4);
  quantize_x<<<2048, 256, 0, stream>>>((const float4*)x, (const float4*)smooth,
                                       maxbits, (int*)xq, n4);

  dim3 grid(N_TOT / BN, M_TOT / BM);
  gemm_i8<<<grid, 512, 0, stream>>>(xq, wq8, maxbits, wscale, bias, out);
}